// Round 4
// baseline (1878.896 us; speedup 1.0000x reference)
//
#include <hip/hip_runtime.h>
#include <math.h>

#define HDIM 512
#define NHEAD 8
#define NLAYER 6
#define SEQ 2048
#define BATCH 2
#define DHEAD 64
#define TOKENS (BATCH*SEQ)
#define FFND (4*HDIM)
#define QSTR 1536   // fused QKV row stride

typedef unsigned short u16;
typedef unsigned long long u64;
typedef __attribute__((ext_vector_type(8))) short short8;
typedef __attribute__((ext_vector_type(4))) float f32x4;

__device__ __forceinline__ u16 f2b(float f) {
  unsigned u = __float_as_uint(f);
  u += 0x7FFFu + ((u >> 16) & 1u);
  return (u16)(u >> 16);
}

__device__ __forceinline__ unsigned cvtpk_bf16(float lo, float hi) {
  unsigned r;
  asm("v_cvt_pk_bf16_f32 %0, %1, %2" : "=v"(r) : "v"(lo), "v"(hi));
  return r;
}

__device__ __forceinline__ void gload_lds16(const u16* g, u16* l) {
  __builtin_amdgcn_global_load_lds((const __attribute__((address_space(1))) void*)g,
                                   (__attribute__((address_space(3))) void*)l, 16, 0, 0);
}

// ---------------- embed + positional encoding ----------------
__global__ void embed_pe(const int* __restrict__ src, const float* __restrict__ emb,
                         float* __restrict__ X, u16* __restrict__ Xb) {
  int tok = blockIdx.x;
  int lane = threadIdx.x;           // 64 threads
  int s = tok & (SEQ - 1);
  int c0 = lane * 8;
  const float* e = emb + (long)src[tok] * HDIM + c0;
  float v[8];
#pragma unroll
  for (int j = 0; j < 8; j++) {
    int c = c0 + j;
    float arg = (float)s * exp2f(-(float)(c & ~1) * 0.02595256917f);
    v[j] = e[j] + ((c & 1) ? cosf(arg) : sinf(arg));
  }
  float* xp = X + (long)tok * HDIM + c0;
#pragma unroll
  for (int j = 0; j < 8; j++) xp[j] = v[j];
  u16 hb[8];
#pragma unroll
  for (int j = 0; j < 8; j++) hb[j] = f2b(v[j]);
  uint4 pk;
  pk.x = hb[0] | ((unsigned)hb[1] << 16);
  pk.y = hb[2] | ((unsigned)hb[3] << 16);
  pk.z = hb[4] | ((unsigned)hb[5] << 16);
  pk.w = hb[6] | ((unsigned)hb[7] << 16);
  *(uint4*)(Xb + (long)tok * HDIM + c0) = pk;
}

// ---------------- mask -> per-64-key-tile bitmasks + pair-counter init ----------------
__global__ void maskprep(const int* __restrict__ mask, u64* __restrict__ mb,
                         int* __restrict__ cnt) {
  int t = threadIdx.x;              // 64 threads: b = t>>5, tile = t&31
  int b = t >> 5, tile = t & 31;
  const int* m = mask + b * SEQ + tile * 64;
  u64 w = 0;
#pragma unroll
  for (int j = 0; j < 64; j++) w |= (u64)(m[j] != 0) << j;
  mb[t] = w;
#pragma unroll
  for (int j = 0; j < 8; j++) cnt[t * 8 + j] = 0;   // 512 pair counters
}

// ---------------- per-layer weight prep: fp32 [K][N] -> bf16 [N][K] ----------------
__global__ __launch_bounds__(256) void prep_weights(
    const float* __restrict__ Wq, const float* __restrict__ Wk, const float* __restrict__ Wv,
    const float* __restrict__ Wo, const float* __restrict__ W1, const float* __restrict__ W2,
    const float* __restrict__ bq, const float* __restrict__ bk, const float* __restrict__ bv,
    u16* __restrict__ Wqkvt, u16* __restrict__ Wot, u16* __restrict__ W1t, u16* __restrict__ W2t,
    float* __restrict__ bqkv) {
  int t = blockIdx.x;
  int tid = threadIdx.x;
  if (t == 768) {
    for (int i = tid; i < 1536; i += 256)
      bqkv[i] = (i < 512) ? bq[i] : (i < 1024) ? bk[i - 512] : bv[i - 1024];
    return;
  }
  const float* src; u16* dst; int K, N, kt, nt; long drow0 = 0;
  if (t < 192)      { int m = t / 64, r = t % 64; src = (m==0)?Wq:(m==1)?Wk:Wv; dst = Wqkvt; drow0 = (long)m*512; K=512;  N=512;  kt=r/8;  nt=r%8; }
  else if (t < 256) { int r = t - 192; src = Wo; dst = Wot; K=512;  N=512;  kt=r/8;  nt=r%8; }
  else if (t < 512) { int r = t - 256; src = W1; dst = W1t; K=512;  N=2048; kt=r/32; nt=r%32; }
  else              { int r = t - 512; src = W2; dst = W2t; K=2048; N=512;  kt=r/8;  nt=r%8; }
  __shared__ __align__(16) u16 Lt[64 * 72];
  int kl = tid >> 2;                 // local k row 0..63
#pragma unroll
  for (int rr = 0; rr < 4; rr++) {
    int cl = (tid & 3) * 4 + rr * 16;  // local n col
    float4 v = *(const float4*)(src + (long)(kt * 64 + kl) * N + nt * 64 + cl);
    Lt[(cl + 0) * 72 + kl] = f2b(v.x);
    Lt[(cl + 1) * 72 + kl] = f2b(v.y);
    Lt[(cl + 2) * 72 + kl] = f2b(v.z);
    Lt[(cl + 3) * 72 + kl] = f2b(v.w);
  }
  __syncthreads();
  int nl = tid >> 2;                 // out row (n) 0..63
  int kc = (tid & 3) * 16;           // out col chunk (k)
  u16* dp = dst + (drow0 + nt * 64 + nl) * (long)K + kt * 64 + kc;
  *(uint4*)dp       = *(const uint4*)&Lt[nl * 72 + kc];
  *(uint4*)(dp + 8) = *(const uint4*)&Lt[nl * 72 + kc + 8];
}

// ---------------- V transpose: QKV V-region -> Vtb[b][h][d][S] ----------------
__global__ __launch_bounds__(256) void vtranspose(const u16* __restrict__ QKV,
                                                  u16* __restrict__ Vtb) {
  __shared__ __align__(16) u16 Lt[64 * 72];
  int tid = threadIdx.x;
  int bh = blockIdx.y, b = bh >> 3, h = bh & 7;
  int s0 = blockIdx.x * 64;
  const u16* vsrc = QKV + (long)(b * SEQ + s0) * QSTR + 1024 + h * DHEAD;
  int key = tid >> 2, dc = (tid & 3) * 16;
  const u16* vp = vsrc + (long)key * QSTR + dc;
  uint4 v0 = *(const uint4*)vp;
  uint4 v1 = *(const uint4*)(vp + 8);
  unsigned vr[8] = { v0.x, v0.y, v0.z, v0.w, v1.x, v1.y, v1.z, v1.w };
#pragma unroll
  for (int j = 0; j < 8; j++) {
    Lt[(dc + 2 * j) * 72 + key]     = (u16)vr[j];
    Lt[(dc + 2 * j + 1) * 72 + key] = (u16)(vr[j] >> 16);
  }
  __syncthreads();
  int d = tid >> 2, kc = (tid & 3) * 16;
  u16* dst = Vtb + ((long)bh * DHEAD + d) * SEQ + s0 + kc;
  *(uint4*)dst       = *(const uint4*)&Lt[d * 72 + kc];
  *(uint4*)(dst + 8) = *(const uint4*)&Lt[d * 72 + kc + 8];
}

// ---------------- bf16 TN GEMM, double-buffered; BM in {128,64} ----------------
// BM=64/BN=64/KSPLIT=1 replaces the old split-K path: same FLOPs and wave count
// (grid doubles in y), but single fp32 output -> no partial-sum round trip.
template <int BM, int BN, int KSPLIT, bool RELU, bool WF32, bool WB16>
__global__ __launch_bounds__(256) void gemm_tn(const u16* __restrict__ A,
                                               const u16* __restrict__ Bt,
                                               const float* __restrict__ bias,
                                               float* __restrict__ Cf,
                                               u16* __restrict__ Cb,
                                               int M, int N, int K) {
  constexpr int NF = BN / 32;                 // n-frags per wave
  constexpr int MF = BM / 32;                 // m-frags per wave
  __shared__ __align__(16) u16 As[2][BM * 32];
  __shared__ __align__(16) u16 Bs[2][BN * 32];
  int tid = threadIdx.x;
  int wave = tid >> 6, lane = tid & 63;
  int ln = lane & 15, hi = lane >> 4;
  int wm = wave >> 1, wn = wave & 1;
  int m0 = blockIdx.y * BM, n0 = blockIdx.x * BN;
  int z = (KSPLIT > 1) ? blockIdx.z : 0;
  int Ks = K / KSPLIT;
  const u16* Ab = A + z * Ks;
  const u16* Bb = Bt + z * Ks;

  f32x4 acc[MF][NF] = {};

  int srow = lane >> 2;        // 0..15
  int skc  = (lane & 3) * 8;   // k-chunk within 32

  auto issue = [&](int kt, int buf) {
    int k0 = kt * 32;
#pragma unroll
    for (int j = 0; j < BM / 64; j++) {
      int row = (wave * (BM / 64) + j) * 16 + srow;
      gload_lds16(Ab + (long)(m0 + row) * K + k0 + skc, &As[buf][row * 32 + skc]);
    }
#pragma unroll
    for (int j = 0; j < BN / 64; j++) {
      int row = (wave * (BN / 64) + j) * 16 + srow;
      gload_lds16(Bb + (long)(n0 + row) * K + k0 + skc, &Bs[buf][row * 32 + skc]);
    }
  };

  int NT = Ks / 32;
  issue(0, 0);
  __syncthreads();
  for (int kt = 0; kt < NT; kt++) {
    int buf = kt & 1;
    if (kt + 1 < NT) issue(kt + 1, buf ^ 1);
    short8 af[MF], bf[NF];
#pragma unroll
    for (int mt = 0; mt < MF; mt++)
      af[mt] = *(const short8*)&As[buf][(wm * (BM / 2) + mt * 16 + ln) * 32 + 8 * hi];
#pragma unroll
    for (int nt = 0; nt < NF; nt++)
      bf[nt] = *(const short8*)&Bs[buf][(wn * (BN / 2) + nt * 16 + ln) * 32 + 8 * hi];
#pragma unroll
    for (int mt = 0; mt < MF; mt++)
#pragma unroll
      for (int nt = 0; nt < NF; nt++)
        acc[mt][nt] = __builtin_amdgcn_mfma_f32_16x16x32_bf16(af[mt], bf[nt], acc[mt][nt], 0, 0, 0);
    __syncthreads();
  }

  float* Cz = WF32 ? (Cf + (long)z * M * N) : nullptr;
#pragma unroll
  for (int mt = 0; mt < MF; mt++)
#pragma unroll
    for (int nt = 0; nt < NF; nt++)
#pragma unroll
      for (int r = 0; r < 4; r++) {
        int row = m0 + wm * (BM / 2) + mt * 16 + hi * 4 + r;
        int col = n0 + wn * (BN / 2) + nt * 16 + ln;
        float v = acc[mt][nt][r];
        if (KSPLIT == 1 || z == 0) v += bias[col];
        if (RELU) v = fmaxf(v, 0.0f);
        if (WF32) Cz[(long)row * N + col] = v;
        if (WB16) Cb[(long)row * N + col] = f2b(v);
      }
}

// ---------------- flash attention, key-split-2, fused last-block merge ----------------
// As R3: swapped QK^T, key bit-permutation, chunk-XOR LDS swizzle, u64 mask
// bitmasks, 2-deep prefetch with counted vmcnt, XCD-contiguous swizzle.
// New: both pair blocks write fp32 partials; the SECOND finisher (device-scope
// atomicAdd parity on a per-pair counter; pairs are same-XCD by the swizzle)
// adds the partner partial from L2, divides by (l0+l1), writes bf16 AVb via the
// LDS-transpose coalesced store.  s_setprio(1) wraps the MFMA clusters.
__global__ __launch_bounds__(256) void attention(const u16* __restrict__ QKV,
                                                 const u16* __restrict__ Vtb,
                                                 const u64* __restrict__ maskb,
                                                 float* __restrict__ Opart,
                                                 float* __restrict__ Lpart,
                                                 int* __restrict__ cnt,
                                                 u16* __restrict__ Og) {
  __shared__ __align__(16) u16 Ks[2][64 * 64];  // [buf][slot][d]  (chunk-swizzled)
  __shared__ __align__(16) u16 Vs[2][64 * 64];  // [buf][d][key]   (chunk-swizzled)
  __shared__ u64 Msk[SEQ / 64];
  __shared__ int oldv;
  int tid = threadIdx.x, w = tid >> 6, lane = tid & 63;
  int ln = lane & 15, hi = lane >> 4;
  int h0 = hi & 1, h1 = hi >> 1, ln7 = ln & 7;
  int lin = blockIdx.x;                        // 1024 blocks, 1-D
  int lid = (lin & 7) * 128 + (lin >> 3);      // bijective XCD-contiguous swizzle
  int bh = lid >> 6, qt = (lid >> 1) & 31, kz = lid & 1;
  int b = bh >> 3, h = bh & 7;
  int q0 = qt * 64 + w * 16;
  const u16* qbase = QKV + (long)b * SEQ * QSTR + h * DHEAD;
  const u16* kbase = qbase + 512;
  const u16* vtbase = Vtb + (long)bh * DHEAD * SEQ;

  // Q fragment (B-operand): lane holds Q[q0+ln][ks*32 + 8*hi .. +7]
  short8 qf[2];
#pragma unroll
  for (int ks = 0; ks < 2; ks++)
    qf[ks] = *(const short8*)(qbase + (long)(q0 + ln) * QSTR + ks * 32 + 8 * hi);

  u64 mw0 = 0;
  if (tid < SEQ / 64) mw0 = maskb[b * (SEQ / 64) + tid];

  // staging geometry: 256 thr x 16B x 2 issues = 8KB per tile per buffer
  int sr0 = tid >> 3, sc = tid & 7;
  const u16 *kp0, *kp1, *vp0, *vp1;
  {
    int r1 = sr0 + 32;
    int key0 = (sr0 & 7) | ((sr0 & 0x18) << 1) | ((sr0 & 0x20) >> 2);
    int key1 = (r1 & 7) | ((r1 & 0x18) << 1) | ((r1 & 0x20) >> 2);
    kp0 = kbase + (long)key0 * QSTR + (sc ^ (sr0 & 7)) * 8;
    kp1 = kbase + (long)key1 * QSTR + (sc ^ (r1 & 7)) * 8;
    vp0 = vtbase + (long)sr0 * SEQ + (sc ^ (sr0 & 7)) * 8;
    vp1 = vtbase + (long)r1 * SEQ + (sc ^ (r1 & 7)) * 8;
  }
  int d0 = sr0 * 64 + sc * 8, d1 = d0 + 2048;

  auto issue = [&](int t, int buf) {
    long ko = (long)t * (64 * QSTR);
    int vo = t * 64;
    gload_lds16(kp0 + ko, &Ks[buf][d0]);
    gload_lds16(kp1 + ko, &Ks[buf][d1]);
    gload_lds16(vp0 + vo, &Vs[buf][d0]);
    gload_lds16(vp1 + vo, &Vs[buf][d1]);
  };

  f32x4 o[4] = {};
  float lsum = 0.0f;
  const int t0 = kz * 16;
  const int NTL = 16;                          // tiles per block (key-split half)

  issue(t0, 0);
  issue(t0 + 1, 1);
  if (tid < SEQ / 64) Msk[tid] = mw0;
  asm volatile("s_waitcnt vmcnt(4)" ::: "memory");   // tile t0 (+q,+mask) done; t0+1 in flight
  __builtin_amdgcn_sched_barrier(0);
  __builtin_amdgcn_s_barrier();
  __builtin_amdgcn_sched_barrier(0);

  for (int ti = 0; ti < NTL; ti++) {
    int buf = ti & 1;
    u64 mw = Msk[t0 + ti];

    // S^T: s[kb][r] = S[q=ln][slot = kb*16 + hi*4 + r]
    f32x4 s[4] = {};
    __builtin_amdgcn_s_setprio(1);
#pragma unroll
    for (int ks = 0; ks < 2; ks++)
#pragma unroll
      for (int kb = 0; kb < 4; kb++) {
        short8 kf = *(const short8*)&Ks[buf][(kb * 16 + ln) * 64 + (((ks << 2) + hi) ^ ln7) * 8];
        s[kb] = __builtin_amdgcn_mfma_f32_16x16x32_bf16(kf, qf[ks], s[kb], 0, 0, 0);
      }
    __builtin_amdgcn_s_setprio(0);

    // softmax numerator + pack to bf16 pairs
    unsigned D[4][2];
    if (mw == 0xFFFFFFFFFFFFFFFFull) {
#pragma unroll
      for (int kb = 0; kb < 4; kb++) {
        float p[4];
#pragma unroll
        for (int r = 0; r < 4; r++) {
          float pv = __expf(s[kb][r] * 0.125f);
          lsum += pv;
          p[r] = pv;
        }
        D[kb][0] = cvtpk_bf16(p[0], p[1]);
        D[kb][1] = cvtpk_bf16(p[2], p[3]);
      }
    } else {
      // lane's key bit positions: 16*h1 + 4*h0 + {0,32,8,40}[kb] + r
      unsigned shb = h1 * 16 + h0 * 4;
      u64 mws = mw >> shb;
      unsigned nib[4] = { (unsigned)mws & 0xFu, (unsigned)(mws >> 32) & 0xFu,
                          (unsigned)(mws >> 8) & 0xFu, (unsigned)(mws >> 40) & 0xFu };
#pragma unroll
      for (int kb = 0; kb < 4; kb++) {
        float p[4];
#pragma unroll
        for (int r = 0; r < 4; r++) {
          float pv = __expf(s[kb][r] * 0.125f);
          pv = ((nib[kb] >> r) & 1u) ? pv : 0.0f;
          lsum += pv;
          p[r] = pv;
        }
        D[kb][0] = cvtpk_bf16(p[0], p[1]);
        D[kb][1] = cvtpk_bf16(p[2], p[3]);
      }
    }

    // assemble PV B-fragments: pb[ks] = P^T[keys 32ks+8hi..+7][q=ln]
    short8 pb[2];
#pragma unroll
    for (int ks = 0; ks < 2; ks++) {
      unsigned own0 = h0 ? D[2 + ks][0] : D[ks][0];
      unsigned own1 = h0 ? D[2 + ks][1] : D[ks][1];
      unsigned snd0 = h0 ? D[ks][0] : D[2 + ks][0];
      unsigned snd1 = h0 ? D[ks][1] : D[2 + ks][1];
      unsigned rc0 = (unsigned)__shfl_xor((int)snd0, 16);
      unsigned rc1 = (unsigned)__shfl_xor((int)snd1, 16);
      union { unsigned u[4]; short8 v; } pu;
      pu.u[0] = h0 ? rc0 : own0;
      pu.u[1] = h0 ? rc1 : own1;
      pu.u[2] = h0 ? own0 : rc0;
      pu.u[3] = h0 ? own1 : rc1;
      pb[ks] = pu.v;
    }

    // O^T += V^T @ P^T : o[mb][r] = O[q=ln][d = mb*16 + hi*4 + r]
    __builtin_amdgcn_s_setprio(1);
#pragma unroll
    for (int ks = 0; ks < 2; ks++)
#pragma unroll
      for (int mb = 0; mb < 4; mb++) {
        short8 vf = *(const short8*)&Vs[buf][(mb * 16 + ln) * 64 + (((ks << 2) + hi) ^ ln7) * 8];
        o[mb] = __builtin_amdgcn_mfma_f32_16x16x32_bf16(vf, pb[ks], o[mb], 0, 0, 0);
      }
    __builtin_amdgcn_s_setprio(0);

    // barrier #1: all waves done READING buf (own ds reads drained first)
    asm volatile("s_waitcnt lgkmcnt(0)" ::: "memory");
    __builtin_amdgcn_sched_barrier(0);
    __builtin_amdgcn_s_barrier();
    __builtin_amdgcn_sched_barrier(0);
    // prefetch ti+2 into buf; wait only until ti+1's loads are home
    if (ti + 2 < NTL) {
      issue(t0 + ti + 2, buf);
      asm volatile("s_waitcnt vmcnt(4)" ::: "memory");
    } else {
      asm volatile("s_waitcnt vmcnt(0)" ::: "memory");
    }
    __builtin_amdgcn_sched_barrier(0);
    __builtin_amdgcn_s_barrier();   // barrier #2: tile ti+1 staged for everyone
    __builtin_amdgcn_sched_barrier(0);
  }

  // partial row-sums: combine over hi groups -> every lane has row total
  lsum += __shfl_xor(lsum, 16);
  lsum += __shfl_xor(lsum, 32);

  // write fp32 partials (block-contiguous [64 q][64 d]) + lsum partials
  float* OpB = Opart + (long)lid * 4096 + w * 1024;
#pragma unroll
  for (int mb = 0; mb < 4; mb++)
    *(f32x4*)&OpB[ln * 64 + mb * 16 + hi * 4] = o[mb];
  if (hi == 0) Lpart[(long)lid * 64 + w * 16 + ln] = lsum;

  // last-arriver-of-pair merges (threadfence-reduction idiom)
  __threadfence();
  __syncthreads();
  if (tid == 0) oldv = atomicAdd(&cnt[lid >> 1], 1);
  __syncthreads();
  if ((oldv & 1) == 0) return;     // first arriver: partner will merge
  __threadfence();                 // acquire partner's partials

  int lidp = lid ^ 1;
  const float* PpB = Opart + (long)lidp * 4096 + w * 1024;
  float lp = Lpart[(long)lidp * 64 + w * 16 + ln];
  float rl = 1.0f / (lsum + lp);

  // coalesced store via LDS transpose (reuse Ks[0]; 1KB per wave)
  u16* Ot = &Ks[0][0] + w * 1024;
#pragma unroll
  for (int mb = 0; mb < 4; mb++) {
    f32x4 po = *(const f32x4*)&PpB[ln * 64 + mb * 16 + hi * 4];
    *(unsigned*)&Ot[ln * 64 + mb * 16 + hi * 4 + 0] =
        cvtpk_bf16((o[mb][0] + po[0]) * rl, (o[mb][1] + po[1]) * rl);
    *(unsigned*)&Ot[ln * 64 + mb * 16 + hi * 4 + 2] =
        cvtpk_bf16((o[mb][2] + po[2]) * rl, (o[mb][3] + po[3]) * rl);
  }
  asm volatile("s_waitcnt lgkmcnt(0)" ::: "memory");
  __builtin_amdgcn_s_barrier();
  u16* obase = Og + (long)b * SEQ * HDIM + (long)qt * 64 * HDIM + h * DHEAD;
#pragma unroll
  for (int pass = 0; pass < 2; pass++) {
    int row = (lane >> 3) + 8 * pass;
    int c = lane & 7;
    uint4 val = *(const uint4*)&Ot[(w * 16 + row) * 64 + c * 8 - w * 1024 + w * 1024];
    // (w*16+row within this wave's Ot block)
    val = *(const uint4*)&Ot[row * 64 + c * 8];
    *(uint4*)(obase + (long)(w * 16 + row) * HDIM + c * 8) = val;
  }
}

// ---------------- residual + LayerNorm over single fp32 sublayer output ----------------
__global__ __launch_bounds__(256) void ln_residual(const float* __restrict__ Xin,
                                                   const float* __restrict__ T0,
                                                   const float* __restrict__ gamma,
                                                   const float* __restrict__ beta,
                                                   float* __restrict__ Xout,
                                                   u16* __restrict__ Xb) {
  int tid = threadIdx.x, w = tid >> 6, lane = tid & 63;
  int row = blockIdx.x * 4 + w;
  const float* t0 = T0 + (long)row * HDIM;
  int c0 = lane * 8;
  float v[8];
  {
    float4 a0 = *(const float4*)(t0 + c0);
    float4 b0 = *(const float4*)(t0 + c0 + 4);
    v[0] = a0.x; v[1] = a0.y; v[2] = a0.z; v[3] = a0.w;
    v[4] = b0.x; v[5] = b0.y; v[6] = b0.z; v[7] = b0.w;
  }
  float sum = 0.0f;
#pragma unroll
  for (int j = 0; j < 8; j++) sum += v[j];
#pragma unroll
  for (int off = 32; off; off >>= 1) sum += __shfl_xor(sum, off);
  float mu = sum * (1.0f / HDIM);
  float sq = 0.0f;
#pragma unroll
  for (int j = 0; j < 8; j++) { float d = v[j] - mu; sq += d * d; }
#pragma unroll
  for (int off = 32; off; off >>= 1) sq += __shfl_xor(sq, off);
  float rs = rsqrtf(sq * (1.0f / HDIM) + 1e-5f);
  const float* xin = Xin + (long)row * HDIM + c0;
  float* xout = Xout + (long)row * HDIM + c0;
  u16 hb[8];
#pragma unroll
  for (int j = 0; j < 8; j++) {
    int c = c0 + j;
    float y = xin[j] + (v[j] - mu) * rs * gamma[c] + beta[c];
    xout[j] = y;
    hb[j] = f2b(y);
  }
  uint4 pk;
  pk.x = hb[0] | ((unsigned)hb[1] << 16);
  pk.y = hb[2] | ((unsigned)hb[3] << 16);
  pk.z = hb[4] | ((unsigned)hb[5] << 16);
  pk.w = hb[6] | ((unsigned)hb[7] << 16);
  *(uint4*)(Xb + (long)row * HDIM + c0) = pk;
}

// ---------------- launch ----------------
extern "C" void kernel_launch(void* const* d_in, const int* in_sizes, int n_in,
                              void* d_out, int out_size, void* d_ws, size_t ws_size,
                              hipStream_t stream) {
  const int*   src   = (const int*)d_in[0];
  const int*   mask  = (const int*)d_in[1];
  const float* emb   = (const float*)d_in[2];
  const float* Wq    = (const float*)d_in[3];
  const float* bq    = (const float*)d_in[4];
  const float* Wk    = (const float*)d_in[5];
  const float* bk    = (const float*)d_in[6];
  const float* Wv    = (const float*)d_in[7];
  const float* bv    = (const float*)d_in[8];
  const float* Wo    = (const float*)d_in[9];
  const float* bo    = (const float*)d_in[10];
  const float* gamma = (const float*)d_in[11];
  const float* beta  = (const float*)d_in[12];
  const float* W1    = (const float*)d_in[13];
  const float* b1    = (const float*)d_in[14];
  const float* W2    = (const float*)d_in[15];
  const float* b2    = (const float*)d_in[16];

  char* ws = (char*)d_ws;
  float* X     = (float*)(ws);                     // 0..8MB   fp32 residual
  u16*   Xb    = (u16*)(ws + (8ll << 20));         // 8..12MB  bf16 mirror
  u16*   QKVb  = (u16*)(ws + (12ll << 20));        // 12..24MB fused QKV bf16
  u16*   Mb    = (u16*)(ws + (12ll << 20));        // 12..28MB FFN mid (reuses QKV+AV)
  u16*   AVb   = (u16*)(ws + (24ll << 20));        // 24..28MB attn out bf16
  float* T     = (float*)(ws + (28ll << 20));      // 28..44MB fp32 sublayer out / attn partials
  u16*   Wqkvt = (u16*)(ws + (44ll << 20));        // 1.5MB
  u16*   Wot   = (u16*)(ws + (45ll << 20) + (512ll << 10)); // 0.5MB
  u16*   W1t   = (u16*)(ws + (46ll << 20));        // 2MB
  u16*   W2t   = (u16*)(ws + (48ll << 20));        // 2MB
  float* bqkv  = (float*)(ws + (50ll << 20));      // 6KB
  float* Lpart = (float*)(ws + (50ll << 20) + (512ll << 10)); // 256KB attn lsum partials
  u16*   Vtb   = (u16*)(ws + (51ll << 20));        // 4MB V^T [b][h][d][S]
  u64*   maskbits = (u64*)(ws + (55ll << 20));     // 512B per-tile mask bitmasks
  int*   cnt   = (int*)(ws + (55ll << 20) + 4096); // 2KB pair counters
  float* Opart = T;                                // attn fp32 O partials (T is dead here)

  embed_pe<<<dim3(TOKENS), dim3(64), 0, stream>>>(src, emb, X, Xb);
  maskprep<<<dim3(1), dim3(64), 0, stream>>>(mask, maskbits, cnt);

  for (int i = 0; i < NLAYER; i++) {
    long wo = (long)i * HDIM * HDIM;
    prep_weights<<<dim3(769), 256, 0, stream>>>(
        Wq + wo, Wk + wo, Wv + wo, Wo + wo,
        W1 + (long)i * HDIM * FFND, W2 + (long)i * FFND * HDIM,
        bq + i * HDIM, bk + i * HDIM, bv + i * HDIM,
        Wqkvt, Wot, W1t, W2t, bqkv);

    gemm_tn<128, 128, 1, false, false, true><<<dim3(QSTR / 128, TOKENS / 128), 256, 0, stream>>>(
        Xb, Wqkvt, bqkv, nullptr, QKVb, TOKENS, QSTR, HDIM);

    vtranspose<<<dim3(SEQ / 64, BATCH * NHEAD), 256, 0, stream>>>(QKVb, Vtb);

    attention<<<dim3(1024), 256, 0, stream>>>(QKVb, Vtb, maskbits, Opart, Lpart, cnt, AVb);

    gemm_tn<64, 64, 1, false, true, false><<<dim3(HDIM / 64, TOKENS / 64), 256, 0, stream>>>(
        AVb, Wot, bo + i * HDIM, T, nullptr, TOKENS, HDIM, HDIM);

    ln_residual<<<dim3(TOKENS / 4), 256, 0, stream>>>(X, T, gamma + i * HDIM,
                                                      beta + i * HDIM, X, Xb);

    gemm_tn<128, 128, 1, true, false, true><<<dim3(FFND / 128, TOKENS / 128), 256, 0, stream>>>(
        Xb, W1t, b1 + (long)i * FFND, nullptr, Mb, TOKENS, FFND, HDIM);

    gemm_tn<64, 64, 1, false, true, false><<<dim3(HDIM / 64, TOKENS / 64), 256, 0, stream>>>(
        Mb, W2t, b2 + i * HDIM, T, nullptr, TOKENS, HDIM, FFND);

    ln_residual<<<dim3(TOKENS / 4), 256, 0, stream>>>(X, T, gamma + i * HDIM,
                                                      beta + i * HDIM, X, Xb);
  }

  hipMemcpyAsync(d_out, X, (size_t)TOKENS * HDIM * sizeof(float),
                 hipMemcpyDeviceToDevice, stream);
}

// Round 5
// 946.126 us; speedup vs baseline: 1.9859x; 1.9859x over previous
//
#include <hip/hip_runtime.h>
#include <math.h>

#define HDIM 512
#define NHEAD 8
#define NLAYER 6
#define SEQ 2048
#define BATCH 2
#define DHEAD 64
#define TOKENS (BATCH*SEQ)
#define FFND (4*HDIM)
#define QSTR 1536   // fused QKV row stride

typedef unsigned short u16;
typedef unsigned long long u64;
typedef __attribute__((ext_vector_type(8))) short short8;
typedef __attribute__((ext_vector_type(4))) float f32x4;

__device__ __forceinline__ u16 f2b(float f) {
  unsigned u = __float_as_uint(f);
  u += 0x7FFFu + ((u >> 16) & 1u);
  return (u16)(u >> 16);
}

__device__ __forceinline__ unsigned cvtpk_bf16(float lo, float hi) {
  unsigned r;
  asm("v_cvt_pk_bf16_f32 %0, %1, %2" : "=v"(r) : "v"(lo), "v"(hi));
  return r;
}

__device__ __forceinline__ void gload_lds16(const u16* g, u16* l) {
  __builtin_amdgcn_global_load_lds((const __attribute__((address_space(1))) void*)g,
                                   (__attribute__((address_space(3))) void*)l, 16, 0, 0);
}

// ---------------- embed + positional encoding ----------------
__global__ void embed_pe(const int* __restrict__ src, const float* __restrict__ emb,
                         float* __restrict__ X, u16* __restrict__ Xb) {
  int tok = blockIdx.x;
  int lane = threadIdx.x;           // 64 threads
  int s = tok & (SEQ - 1);
  int c0 = lane * 8;
  const float* e = emb + (long)src[tok] * HDIM + c0;
  float v[8];
#pragma unroll
  for (int j = 0; j < 8; j++) {
    int c = c0 + j;
    float arg = (float)s * exp2f(-(float)(c & ~1) * 0.02595256917f);
    v[j] = e[j] + ((c & 1) ? cosf(arg) : sinf(arg));
  }
  float* xp = X + (long)tok * HDIM + c0;
#pragma unroll
  for (int j = 0; j < 8; j++) xp[j] = v[j];
  u16 hb[8];
#pragma unroll
  for (int j = 0; j < 8; j++) hb[j] = f2b(v[j]);
  uint4 pk;
  pk.x = hb[0] | ((unsigned)hb[1] << 16);
  pk.y = hb[2] | ((unsigned)hb[3] << 16);
  pk.z = hb[4] | ((unsigned)hb[5] << 16);
  pk.w = hb[6] | ((unsigned)hb[7] << 16);
  *(uint4*)(Xb + (long)tok * HDIM + c0) = pk;
}

// ---------------- mask -> per-64-key-tile bitmasks (once per net) ----------------
__global__ void maskprep(const int* __restrict__ mask, u64* __restrict__ mb) {
  int t = threadIdx.x;              // 64 threads: b = t>>5, tile = t&31
  int b = t >> 5, tile = t & 31;
  const int* m = mask + b * SEQ + tile * 64;
  u64 w = 0;
#pragma unroll
  for (int j = 0; j < 64; j++) w |= (u64)(m[j] != 0) << j;
  mb[t] = w;
}

// ---------------- per-layer weight prep: fp32 [K][N] -> bf16 [N][K] ----------------
__global__ __launch_bounds__(256) void prep_weights(
    const float* __restrict__ Wq, const float* __restrict__ Wk, const float* __restrict__ Wv,
    const float* __restrict__ Wo, const float* __restrict__ W1, const float* __restrict__ W2,
    const float* __restrict__ bq, const float* __restrict__ bk, const float* __restrict__ bv,
    u16* __restrict__ Wqkvt, u16* __restrict__ Wot, u16* __restrict__ W1t, u16* __restrict__ W2t,
    float* __restrict__ bqkv) {
  int t = blockIdx.x;
  int tid = threadIdx.x;
  if (t == 768) {
    for (int i = tid; i < 1536; i += 256)
      bqkv[i] = (i < 512) ? bq[i] : (i < 1024) ? bk[i - 512] : bv[i - 1024];
    return;
  }
  const float* src; u16* dst; int K, N, kt, nt; long drow0 = 0;
  if (t < 192)      { int m = t / 64, r = t % 64; src = (m==0)?Wq:(m==1)?Wk:Wv; dst = Wqkvt; drow0 = (long)m*512; K=512;  N=512;  kt=r/8;  nt=r%8; }
  else if (t < 256) { int r = t - 192; src = Wo; dst = Wot; K=512;  N=512;  kt=r/8;  nt=r%8; }
  else if (t < 512) { int r = t - 256; src = W1; dst = W1t; K=512;  N=2048; kt=r/32; nt=r%32; }
  else              { int r = t - 512; src = W2; dst = W2t; K=2048; N=512;  kt=r/8;  nt=r%8; }
  __shared__ __align__(16) u16 Lt[64 * 72];
  int kl = tid >> 2;                 // local k row 0..63
#pragma unroll
  for (int rr = 0; rr < 4; rr++) {
    int cl = (tid & 3) * 4 + rr * 16;  // local n col
    float4 v = *(const float4*)(src + (long)(kt * 64 + kl) * N + nt * 64 + cl);
    Lt[(cl + 0) * 72 + kl] = f2b(v.x);
    Lt[(cl + 1) * 72 + kl] = f2b(v.y);
    Lt[(cl + 2) * 72 + kl] = f2b(v.z);
    Lt[(cl + 3) * 72 + kl] = f2b(v.w);
  }
  __syncthreads();
  int nl = tid >> 2;                 // out row (n) 0..63
  int kc = (tid & 3) * 16;           // out col chunk (k)
  u16* dp = dst + (drow0 + nt * 64 + nl) * (long)K + kt * 64 + kc;
  *(uint4*)dp       = *(const uint4*)&Lt[nl * 72 + kc];
  *(uint4*)(dp + 8) = *(const uint4*)&Lt[nl * 72 + kc + 8];
}

// ---------------- V transpose: QKV V-region -> Vtb[b][h][d][S] ----------------
__global__ __launch_bounds__(256) void vtranspose(const u16* __restrict__ QKV,
                                                  u16* __restrict__ Vtb) {
  __shared__ __align__(16) u16 Lt[64 * 72];
  int tid = threadIdx.x;
  int bh = blockIdx.y, b = bh >> 3, h = bh & 7;
  int s0 = blockIdx.x * 64;
  const u16* vsrc = QKV + (long)(b * SEQ + s0) * QSTR + 1024 + h * DHEAD;
  int key = tid >> 2, dc = (tid & 3) * 16;
  const u16* vp = vsrc + (long)key * QSTR + dc;
  uint4 v0 = *(const uint4*)vp;
  uint4 v1 = *(const uint4*)(vp + 8);
  unsigned vr[8] = { v0.x, v0.y, v0.z, v0.w, v1.x, v1.y, v1.z, v1.w };
#pragma unroll
  for (int j = 0; j < 8; j++) {
    Lt[(dc + 2 * j) * 72 + key]     = (u16)vr[j];
    Lt[(dc + 2 * j + 1) * 72 + key] = (u16)(vr[j] >> 16);
  }
  __syncthreads();
  int d = tid >> 2, kc = (tid & 3) * 16;
  u16* dst = Vtb + ((long)bh * DHEAD + d) * SEQ + s0 + kc;
  *(uint4*)dst       = *(const uint4*)&Lt[d * 72 + kc];
  *(uint4*)(dst + 8) = *(const uint4*)&Lt[d * 72 + kc + 8];
}

// ---------------- bf16 TN GEMM, double-buffered; BM in {128,64} ----------------
template <int BM, int BN, bool RELU, bool WF32, bool WB16>
__global__ __launch_bounds__(256) void gemm_tn(const u16* __restrict__ A,
                                               const u16* __restrict__ Bt,
                                               const float* __restrict__ bias,
                                               float* __restrict__ Cf,
                                               u16* __restrict__ Cb,
                                               int M, int N, int K) {
  constexpr int NF = BN / 32;                 // n-frags per wave
  constexpr int MF = BM / 32;                 // m-frags per wave
  __shared__ __align__(16) u16 As[2][BM * 32];
  __shared__ __align__(16) u16 Bs[2][BN * 32];
  int tid = threadIdx.x;
  int wave = tid >> 6, lane = tid & 63;
  int ln = lane & 15, hi = lane >> 4;
  int wm = wave >> 1, wn = wave & 1;
  int m0 = blockIdx.y * BM, n0 = blockIdx.x * BN;

  f32x4 acc[MF][NF] = {};

  int srow = lane >> 2;        // 0..15
  int skc  = (lane & 3) * 8;   // k-chunk within 32

  auto issue = [&](int kt, int buf) {
    int k0 = kt * 32;
#pragma unroll
    for (int j = 0; j < BM / 64; j++) {
      int row = (wave * (BM / 64) + j) * 16 + srow;
      gload_lds16(A + (long)(m0 + row) * K + k0 + skc, &As[buf][row * 32 + skc]);
    }
#pragma unroll
    for (int j = 0; j < BN / 64; j++) {
      int row = (wave * (BN / 64) + j) * 16 + srow;
      gload_lds16(Bt + (long)(n0 + row) * K + k0 + skc, &Bs[buf][row * 32 + skc]);
    }
  };

  int NT = K / 32;
  issue(0, 0);
  __syncthreads();
  for (int kt = 0; kt < NT; kt++) {
    int buf = kt & 1;
    if (kt + 1 < NT) issue(kt + 1, buf ^ 1);
    short8 af[MF], bf[NF];
#pragma unroll
    for (int mt = 0; mt < MF; mt++)
      af[mt] = *(const short8*)&As[buf][(wm * (BM / 2) + mt * 16 + ln) * 32 + 8 * hi];
#pragma unroll
    for (int nt = 0; nt < NF; nt++)
      bf[nt] = *(const short8*)&Bs[buf][(wn * (BN / 2) + nt * 16 + ln) * 32 + 8 * hi];
#pragma unroll
    for (int mt = 0; mt < MF; mt++)
#pragma unroll
      for (int nt = 0; nt < NF; nt++)
        acc[mt][nt] = __builtin_amdgcn_mfma_f32_16x16x32_bf16(af[mt], bf[nt], acc[mt][nt], 0, 0, 0);
    __syncthreads();
  }

#pragma unroll
  for (int mt = 0; mt < MF; mt++)
#pragma unroll
    for (int nt = 0; nt < NF; nt++)
#pragma unroll
      for (int r = 0; r < 4; r++) {
        int row = m0 + wm * (BM / 2) + mt * 16 + hi * 4 + r;
        int col = n0 + wn * (BN / 2) + nt * 16 + ln;
        float v = acc[mt][nt][r] + bias[col];
        if (RELU) v = fmaxf(v, 0.0f);
        if (WF32) Cf[(long)row * N + col] = v;
        if (WB16) Cb[(long)row * N + col] = f2b(v);
      }
}

// ---------------- flash attention, key-split-2, counted-vmcnt pipeline ----------------
// As R3 (the 998µs-verified structure): swapped QK^T, key bit-permutation,
// chunk-XOR LDS swizzle, u64 mask bitmasks, 2-deep prefetch with counted vmcnt,
// XCD-contiguous swizzle, fp32 partials + separate merge kernel (NO device-scope
// fence: R4 showed __threadfence() forces L2 writeback on non-coherent XCD L2s,
// 199µs vs 33µs).  setprio(1) wraps the MFMA clusters (m191).
__global__ __launch_bounds__(256) void attention(const u16* __restrict__ QKV,
                                                 const u16* __restrict__ Vtb,
                                                 const u64* __restrict__ maskb,
                                                 float* __restrict__ Opart,
                                                 float* __restrict__ Lpart) {
  __shared__ __align__(16) u16 Ks[2][64 * 64];  // [buf][slot][d]  (chunk-swizzled)
  __shared__ __align__(16) u16 Vs[2][64 * 64];  // [buf][d][key]   (chunk-swizzled)
  __shared__ u64 Msk[SEQ / 64];
  int tid = threadIdx.x, w = tid >> 6, lane = tid & 63;
  int ln = lane & 15, hi = lane >> 4;
  int h0 = hi & 1, h1 = hi >> 1, ln7 = ln & 7;
  int lin = blockIdx.x;                        // 1024 blocks, 1-D
  int lid = (lin & 7) * 128 + (lin >> 3);      // bijective XCD-contiguous swizzle
  int bh = lid >> 6, qt = (lid >> 1) & 31, kz = lid & 1;
  int b = bh >> 3, h = bh & 7;
  int q0 = qt * 64 + w * 16;
  const u16* qbase = QKV + (long)b * SEQ * QSTR + h * DHEAD;
  const u16* kbase = qbase + 512;
  const u16* vtbase = Vtb + (long)bh * DHEAD * SEQ;

  // Q fragment (B-operand): lane holds Q[q0+ln][ks*32 + 8*hi .. +7]
  short8 qf[2];
#pragma unroll
  for (int ks = 0; ks < 2; ks++)
    qf[ks] = *(const short8*)(qbase + (long)(q0 + ln) * QSTR + ks * 32 + 8 * hi);

  u64 mw0 = 0;
  if (tid < SEQ / 64) mw0 = maskb[b * (SEQ / 64) + tid];

  // staging geometry: 256 thr x 16B x 2 issues = 8KB per tile per buffer
  int sr0 = tid >> 3, sc = tid & 7;
  const u16 *kp0, *kp1, *vp0, *vp1;
  {
    int r1 = sr0 + 32;
    int key0 = (sr0 & 7) | ((sr0 & 0x18) << 1) | ((sr0 & 0x20) >> 2);
    int key1 = (r1 & 7) | ((r1 & 0x18) << 1) | ((r1 & 0x20) >> 2);
    kp0 = kbase + (long)key0 * QSTR + (sc ^ (sr0 & 7)) * 8;
    kp1 = kbase + (long)key1 * QSTR + (sc ^ (r1 & 7)) * 8;
    vp0 = vtbase + (long)sr0 * SEQ + (sc ^ (sr0 & 7)) * 8;
    vp1 = vtbase + (long)r1 * SEQ + (sc ^ (r1 & 7)) * 8;
  }
  int d0 = sr0 * 64 + sc * 8, d1 = d0 + 2048;

  auto issue = [&](int t, int buf) {
    long ko = (long)t * (64 * QSTR);
    int vo = t * 64;
    gload_lds16(kp0 + ko, &Ks[buf][d0]);
    gload_lds16(kp1 + ko, &Ks[buf][d1]);
    gload_lds16(vp0 + vo, &Vs[buf][d0]);
    gload_lds16(vp1 + vo, &Vs[buf][d1]);
  };

  f32x4 o[4] = {};
  float lsum = 0.0f;
  const int t0 = kz * 16;
  const int NTL = 16;                          // tiles per block (key-split half)

  issue(t0, 0);
  issue(t0 + 1, 1);
  if (tid < SEQ / 64) Msk[tid] = mw0;
  asm volatile("s_waitcnt vmcnt(4)" ::: "memory");   // tile t0 (+q,+mask) done; t0+1 in flight
  __builtin_amdgcn_sched_barrier(0);
  __builtin_amdgcn_s_barrier();
  __builtin_amdgcn_sched_barrier(0);

  for (int ti = 0; ti < NTL; ti++) {
    int buf = ti & 1;
    u64 mw = Msk[t0 + ti];

    // S^T: s[kb][r] = S[q=ln][slot = kb*16 + hi*4 + r]
    f32x4 s[4] = {};
    __builtin_amdgcn_s_setprio(1);
#pragma unroll
    for (int ks = 0; ks < 2; ks++)
#pragma unroll
      for (int kb = 0; kb < 4; kb++) {
        short8 kf = *(const short8*)&Ks[buf][(kb * 16 + ln) * 64 + (((ks << 2) + hi) ^ ln7) * 8];
        s[kb] = __builtin_amdgcn_mfma_f32_16x16x32_bf16(kf, qf[ks], s[kb], 0, 0, 0);
      }
    __builtin_amdgcn_s_setprio(0);

    // softmax numerator + pack to bf16 pairs
    unsigned D[4][2];
    if (mw == 0xFFFFFFFFFFFFFFFFull) {
#pragma unroll
      for (int kb = 0; kb < 4; kb++) {
        float p[4];
#pragma unroll
        for (int r = 0; r < 4; r++) {
          float pv = __expf(s[kb][r] * 0.125f);
          lsum += pv;
          p[r] = pv;
        }
        D[kb][0] = cvtpk_bf16(p[0], p[1]);
        D[kb][1] = cvtpk_bf16(p[2], p[3]);
      }
    } else {
      // lane's key bit positions: 16*h1 + 4*h0 + {0,32,8,40}[kb] + r
      unsigned shb = h1 * 16 + h0 * 4;
      u64 mws = mw >> shb;
      unsigned nib[4] = { (unsigned)mws & 0xFu, (unsigned)(mws >> 32) & 0xFu,
                          (unsigned)(mws >> 8) & 0xFu, (unsigned)(mws >> 40) & 0xFu };
#pragma unroll
      for (int kb = 0; kb < 4; kb++) {
        float p[4];
#pragma unroll
        for (int r = 0; r < 4; r++) {
          float pv = __expf(s[kb][r] * 0.125f);
          pv = ((nib[kb] >> r) & 1u) ? pv : 0.0f;
          lsum += pv;
          p[r] = pv;
        }
        D[kb][0] = cvtpk_bf16(p[0], p[1]);
        D[kb][1] = cvtpk_bf16(p[2], p[3]);
      }
    }

    // assemble PV B-fragments: pb[ks] = P^T[keys 32ks+8hi..+7][q=ln]
    short8 pb[2];
#pragma unroll
    for (int ks = 0; ks < 2; ks++) {
      unsigned own0 = h0 ? D[2 + ks][0] : D[ks][0];
      unsigned own1 = h0 ? D[2 + ks][1] : D[ks][1];
      unsigned snd0 = h0 ? D[ks][0] : D[2 + ks][0];
      unsigned snd1 = h0 ? D[ks][1] : D[2 + ks][1];
      unsigned rc0 = (unsigned)__shfl_xor((int)snd0, 16);
      unsigned rc1 = (unsigned)__shfl_xor((int)snd1, 16);
      union { unsigned u[4]; short8 v; } pu;
      pu.u[0] = h0 ? rc0 : own0;
      pu.u[1] = h0 ? rc1 : own1;
      pu.u[2] = h0 ? own0 : rc0;
      pu.u[3] = h0 ? own1 : rc1;
      pb[ks] = pu.v;
    }

    // O^T += V^T @ P^T : o[mb][r] = O[q=ln][d = mb*16 + hi*4 + r]
    __builtin_amdgcn_s_setprio(1);
#pragma unroll
    for (int ks = 0; ks < 2; ks++)
#pragma unroll
      for (int mb = 0; mb < 4; mb++) {
        short8 vf = *(const short8*)&Vs[buf][(mb * 16 + ln) * 64 + (((ks << 2) + hi) ^ ln7) * 8];
        o[mb] = __builtin_amdgcn_mfma_f32_16x16x32_bf16(vf, pb[ks], o[mb], 0, 0, 0);
      }
    __builtin_amdgcn_s_setprio(0);

    // barrier #1: all waves done READING buf (own ds reads drained first)
    asm volatile("s_waitcnt lgkmcnt(0)" ::: "memory");
    __builtin_amdgcn_sched_barrier(0);
    __builtin_amdgcn_s_barrier();
    __builtin_amdgcn_sched_barrier(0);
    // prefetch ti+2 into buf; wait only until ti+1's loads are home
    if (ti + 2 < NTL) {
      issue(t0 + ti + 2, buf);
      asm volatile("s_waitcnt vmcnt(4)" ::: "memory");
    } else {
      asm volatile("s_waitcnt vmcnt(0)" ::: "memory");
    }
    __builtin_amdgcn_sched_barrier(0);
    __builtin_amdgcn_s_barrier();   // barrier #2: tile ti+1 staged for everyone
    __builtin_amdgcn_sched_barrier(0);
  }

  // partial row-sums: combine over hi groups -> every lane has row total
  lsum += __shfl_xor(lsum, 16);
  lsum += __shfl_xor(lsum, 32);

  // raw fp32 partial O: block-contiguous [64 q][64 d]; f32x4 per (mb)
  float* OpB = Opart + (long)lid * 4096 + w * 1024;
#pragma unroll
  for (int mb = 0; mb < 4; mb++)
    *(f32x4*)&OpB[ln * 64 + mb * 16 + hi * 4] = o[mb];
  if (hi == 0) Lpart[(long)lid * 64 + w * 16 + ln] = lsum;
}

// ---------------- merge key-split partials -> bf16 AVb ----------------
__global__ __launch_bounds__(256) void attn_merge(const float* __restrict__ Op,
                                                  const float* __restrict__ Lp,
                                                  u16* __restrict__ Og) {
  int lin = blockIdx.x;                       // 512 blocks
  int mlid = (lin & 7) * 64 + (lin >> 3);     // XCD-matched swizzle (same L2 as producer)
  int bh = mlid >> 5, qt = mlid & 31;
  int b = bh >> 3, h = bh & 7;
  int tid = threadIdx.x;
  __shared__ float Ls[64];
  if (tid < 64) Ls[tid] = 1.0f / (Lp[(long)mlid * 128 + tid] + Lp[(long)mlid * 128 + 64 + tid]);
  __syncthreads();
  const float* P0 = Op + (long)mlid * 8192;
  const float* P1 = P0 + 4096;
  u16* obase = Og + (long)b * SEQ * HDIM + (long)qt * 64 * HDIM + h * DHEAD;
#pragma unroll
  for (int j = 0; j < 4; j++) {
    int flat = j * 1024 + tid * 4;
    int row = flat >> 6, c = flat & 63;
    float4 a = *(const float4*)&P0[flat];
    float4 bb = *(const float4*)&P1[flat];
    float rl = Ls[row];
    uint2 val;
    val.x = cvtpk_bf16((a.x + bb.x) * rl, (a.y + bb.y) * rl);
    val.y = cvtpk_bf16((a.z + bb.z) * rl, (a.w + bb.w) * rl);
    *(uint2*)(obase + (long)row * HDIM + c) = val;
  }
}

// ---------------- residual + LayerNorm over single fp32 sublayer output ----------------
__global__ __launch_bounds__(256) void ln_residual(const float* __restrict__ Xin,
                                                   const float* __restrict__ T0,
                                                   const float* __restrict__ gamma,
                                                   const float* __restrict__ beta,
                                                   float* __restrict__ Xout,
                                                   u16* __restrict__ Xb) {
  int tid = threadIdx.x, w = tid >> 6, lane = tid & 63;
  int row = blockIdx.x * 4 + w;
  const float* t0 = T0 + (long)row * HDIM;
  int c0 = lane * 8;
  float v[8];
  {
    float4 a0 = *(const float4*)(t0 + c0);
    float4 b0 = *(const float4*)(t0 + c0 + 4);
    v[0] = a0.x; v[1] = a0.y; v[2] = a0.z; v[3] = a0.w;
    v[4] = b0.x; v[5] = b0.y; v[6] = b0.z; v[7] = b0.w;
  }
  float sum = 0.0f;
#pragma unroll
  for (int j = 0; j < 8; j++) sum += v[j];
#pragma unroll
  for (int off = 32; off; off >>= 1) sum += __shfl_xor(sum, off);
  float mu = sum * (1.0f / HDIM);
  float sq = 0.0f;
#pragma unroll
  for (int j = 0; j < 8; j++) { float d = v[j] - mu; sq += d * d; }
#pragma unroll
  for (int off = 32; off; off >>= 1) sq += __shfl_xor(sq, off);
  float rs = rsqrtf(sq * (1.0f / HDIM) + 1e-5f);
  const float* xin = Xin + (long)row * HDIM + c0;
  float* xout = Xout + (long)row * HDIM + c0;
  u16 hb[8];
#pragma unroll
  for (int j = 0; j < 8; j++) {
    int c = c0 + j;
    float y = xin[j] + (v[j] - mu) * rs * gamma[c] + beta[c];
    xout[j] = y;
    hb[j] = f2b(y);
  }
  uint4 pk;
  pk.x = hb[0] | ((unsigned)hb[1] << 16);
  pk.y = hb[2] | ((unsigned)hb[3] << 16);
  pk.z = hb[4] | ((unsigned)hb[5] << 16);
  pk.w = hb[6] | ((unsigned)hb[7] << 16);
  *(uint4*)(Xb + (long)row * HDIM + c0) = pk;
}

// ---------------- launch ----------------
extern "C" void kernel_launch(void* const* d_in, const int* in_sizes, int n_in,
                              void* d_out, int out_size, void* d_ws, size_t ws_size,
                              hipStream_t stream) {
  const int*   src   = (const int*)d_in[0];
  const int*   mask  = (const int*)d_in[1];
  const float* emb   = (const float*)d_in[2];
  const float* Wq    = (const float*)d_in[3];
  const float* bq    = (const float*)d_in[4];
  const float* Wk    = (const float*)d_in[5];
  const float* bk    = (const float*)d_in[6];
  const float* Wv    = (const float*)d_in[7];
  const float* bv    = (const float*)d_in[8];
  const float* Wo    = (const float*)d_in[9];
  const float* bo    = (const float*)d_in[10];
  const float* gamma = (const float*)d_in[11];
  const float* beta  = (const float*)d_in[12];
  const float* W1    = (const float*)d_in[13];
  const float* b1    = (const float*)d_in[14];
  const float* W2    = (const float*)d_in[15];
  const float* b2    = (const float*)d_in[16];

  char* ws = (char*)d_ws;
  float* X     = (float*)(ws);                     // 0..8MB   fp32 residual
  u16*   Xb    = (u16*)(ws + (8ll << 20));         // 8..12MB  bf16 mirror
  u16*   QKVb  = (u16*)(ws + (12ll << 20));        // 12..24MB fused QKV bf16
  u16*   Mb    = (u16*)(ws + (12ll << 20));        // 12..28MB FFN mid (reuses QKV+AV)
  u16*   AVb   = (u16*)(ws + (24ll << 20));        // 24..28MB attn out bf16
  float* T     = (float*)(ws + (28ll << 20));      // 28..44MB fp32 sublayer out / attn partials
  u16*   Wqkvt = (u16*)(ws + (44ll << 20));        // 1.5MB
  u16*   Wot   = (u16*)(ws + (45ll << 20) + (512ll << 10)); // 0.5MB
  u16*   W1t   = (u16*)(ws + (46ll << 20));        // 2MB
  u16*   W2t   = (u16*)(ws + (48ll << 20));        // 2MB
  float* bqkv  = (float*)(ws + (50ll << 20));      // 6KB
  float* Lpart = (float*)(ws + (50ll << 20) + (512ll << 10)); // 256KB attn lsum partials
  u16*   Vtb   = (u16*)(ws + (51ll << 20));        // 4MB V^T [b][h][d][S]
  u64*   maskbits = (u64*)(ws + (55ll << 20));     // 512B per-tile mask bitmasks
  float* Opart = T;                                // attn fp32 O partials (T is dead here)

  embed_pe<<<dim3(TOKENS), dim3(64), 0, stream>>>(src, emb, X, Xb);
  maskprep<<<dim3(1), dim3(64), 0, stream>>>(mask, maskbits);

  for (int i = 0; i < NLAYER; i++) {
    long wo = (long)i * HDIM * HDIM;
    prep_weights<<<dim3(769), 256, 0, stream>>>(
        Wq + wo, Wk + wo, Wv + wo, Wo + wo,
        W1 + (long)i * HDIM * FFND, W2 + (long)i * FFND * HDIM,
        bq + i * HDIM, bk + i * HDIM, bv + i * HDIM,
        Wqkvt, Wot, W1t, W2t, bqkv);

    gemm_tn<128, 128, false, false, true><<<dim3(QSTR / 128, TOKENS / 128), 256, 0, stream>>>(
        Xb, Wqkvt, bqkv, nullptr, QKVb, TOKENS, QSTR, HDIM);

    vtranspose<<<dim3(SEQ / 64, BATCH * NHEAD), 256, 0, stream>>>(QKVb, Vtb);

    attention<<<dim3(1024), 256, 0, stream>>>(QKVb, Vtb, maskbits, Opart, Lpart);

    attn_merge<<<dim3(512), 256, 0, stream>>>(Opart, Lpart, AVb);

    gemm_tn<64, 64, false, true, false><<<dim3(HDIM / 64, TOKENS / 64), 256, 0, stream>>>(
        AVb, Wot, bo + i * HDIM, T, nullptr, TOKENS, HDIM, HDIM);

    ln_residual<<<dim3(TOKENS / 4), 256, 0, stream>>>(X, T, gamma + i * HDIM,
                                                      beta + i * HDIM, X, Xb);

    gemm_tn<128, 128, true, false, true><<<dim3(FFND / 128, TOKENS / 128), 256, 0, stream>>>(
        Xb, W1t, b1 + (long)i * FFND, nullptr, Mb, TOKENS, FFND, HDIM);

    gemm_tn<64, 64, false, true, false><<<dim3(HDIM / 64, TOKENS / 64), 256, 0, stream>>>(
        Mb, W2t, b2 + i * HDIM, T, nullptr, TOKENS, HDIM, FFND);

    ln_residual<<<dim3(TOKENS / 4), 256, 0, stream>>>(X, T, gamma + i * HDIM,
                                                      beta + i * HDIM, X, Xb);
  }

  hipMemcpyAsync(d_out, X, (size_t)TOKENS * HDIM * sizeof(float),
                 hipMemcpyDeviceToDevice, stream);
}